// Round 13
// baseline (66.677 us; speedup 1.0000x reference)
//
#include <hip/hip_runtime.h>
#include <math.h>

#define NTX_EPS 1e-8f

typedef __fp16 half8  __attribute__((ext_vector_type(8)));
typedef __fp16 half4v __attribute__((ext_vector_type(4)));
typedef __fp16 half2v __attribute__((ext_vector_type(2)));
typedef float  f32x4  __attribute__((ext_vector_type(4)));

union H4 { half4v v4; half2v v2[2]; };

// ws layout (floats):
//   [ (b*6+slot)*528 ]       : Gram partials, slots 0..5
//   [ LOSS_OFF + b*3 + lvl ] : per-(batch,level) losses (no atomics; K3 sums)
#define LOSS_OFF (256 * 6 * 528)

// Kernel 1: 1792 blocks x 256 threads (4 waves). Block = (b, slot) owning a
// 1024-float d-chunk, processed as TWO 512-float phases:
//   stage: wave w loads rows w*8..w*8+7, each as 2x fully-CONTIGUOUS 1KB
//          float4 instructions (16 independent loads/wave in flight),
//          cvt_pkrtz -> f16 -> swizzled LDS tile [32][512] f16 (32KB).
//   compute: verified MFMA Gram (R7/R12): lane l feeds row l&15, k-group
//          l>>4; one half8 is both A and B; mfma(t,t)/(t,r)/(r,r).
// LDS swizzle: 16B-chunk c stored at c^(row&15) -> fragment ds_read_b128 is
// 2-way-conflict (free, m136). LDS 33KB -> 4 blocks/CU = 16 waves/CU.
// R13 rationale: 13 structures all pinned at ~10 GB/s/CU reads; copy ubench
// does 24.6. Good-pattern rounds were low-occupancy, high-occupancy rounds
// had bad patterns; this is the untested {copy-shaped x 16 waves/CU} cell.
__global__ __launch_bounds__(256)
void ntxent_partial(const float* __restrict__ ts0, const float* __restrict__ rs0,
                    const float* __restrict__ ts1, const float* __restrict__ rs1,
                    const float* __restrict__ ts2, const float* __restrict__ rs2,
                    float* __restrict__ ws)
{
    __shared__ __align__(16) char smem[33024];
    __fp16* Mt = (__fp16*)smem;                    // 32 rows x 512 f16, swizzled

    const int bid  = blockIdx.x;
    const int b    = bid / 7;
    const int slot = bid % 7;

    const float* tp; const float* rp; int D; int chunk0;
    if (slot < 4)      { tp = ts0; rp = rs0; D = 4096; chunk0 = slot; }
    else if (slot < 6) { tp = ts1; rp = rs1; D = 2048; chunk0 = slot - 4; }
    else               { tp = ts2; rp = rs2; D = 1024; chunk0 = 0; }

    const int t   = threadIdx.x;
    const int w   = t >> 6;
    const int l   = t & 63;
    const int row = l & 15;
    const int kg  = l >> 4;

    // this wave's 8 staged rows (rows 0-15 = ts, 16-31 = rs)
    const float* rowsrc[8];
#pragma unroll
    for (int i = 0; i < 8; ++i) {
        const int r = w * 8 + i;
        rowsrc[i] = (r < 16 ? tp + ((size_t)b * 16 + r) * (size_t)D
                            : rp + ((size_t)b * 16 + (r - 16)) * (size_t)D)
                  + (size_t)chunk0 * 1024;
    }

    f32x4 acc_tt = {0.f, 0.f, 0.f, 0.f};
    f32x4 acc_tr = {0.f, 0.f, 0.f, 0.f};
    f32x4 acc_rr = {0.f, 0.f, 0.f, 0.f};

    for (int p = 0; p < 2; ++p) {
        if (p) __syncthreads();            // phase-0 reads done before overwrite
        // ---- stage: 2 bursts of 8 contiguous-1KB loads ----
#pragma unroll
        for (int j = 0; j < 2; ++j) {
            float4 st[8];
#pragma unroll
            for (int i = 0; i < 8; ++i)
                st[i] = *(const float4*)(rowsrc[i] + p * 512 + j * 256 + l * 4);
#pragma unroll
            for (int i = 0; i < 8; ++i) {
                const int r = w * 8 + i;
                const int chunk = j * 32 + (l >> 1);       // 16B chunk index
                const int cs = chunk ^ (r & 15);           // swizzle
                H4 u;
                u.v2[0] = __builtin_amdgcn_cvt_pkrtz(st[i].x, st[i].y);
                u.v2[1] = __builtin_amdgcn_cvt_pkrtz(st[i].z, st[i].w);
                *(half4v*)((char*)Mt + r * 1024 + cs * 16 + (l & 1) * 8) = u.v4;
            }
        }
        __syncthreads();
        // ---- compute: wave w owns f16 cols [w*128, w*128+128) of this phase ----
#pragma unroll
        for (int sl = 0; sl < 4; ++sl) {
            const int c  = w * 16 + sl * 4 + kg;
            const int cT = c ^ (row & 15);
            half8 tf = *(const half8*)((char*)Mt + row * 1024 + cT * 16);
            half8 rf = *(const half8*)((char*)Mt + (row + 16) * 1024 + cT * 16);
            acc_tt = __builtin_amdgcn_mfma_f32_16x16x32_f16(tf, tf, acc_tt, 0, 0, 0);
            acc_tr = __builtin_amdgcn_mfma_f32_16x16x32_f16(tf, rf, acc_tr, 0, 0, 0);
            acc_rr = __builtin_amdgcn_mfma_f32_16x16x32_f16(rf, rf, acc_rr, 0, 0, 0);
        }
    }
    __syncthreads();                       // Mt dead; smem becomes reduce scratch

    float* redTT = (float*)smem;           // [4][256]
    float* redTR = (float*)(smem + 4096);  // [4][256]
    float* redRR = (float*)(smem + 8192);  // [4][16]
    float* Gs    = (float*)(smem + 8448);  // [16][33]
    float* rn2   = (float*)(smem + 10560); // [16]
    float* tnS   = (float*)(smem + 10624); // [16]
    float* rnS   = (float*)(smem + 10688); // [16]

    // C/D layout (m89): col = l&15, row index = kg*4 + r.
    const int m = row;
#pragma unroll
    for (int r = 0; r < 4; ++r) {
        const int n = kg * 4 + r;
        redTT[w * 256 + n * 16 + m] = acc_tt[r];
        redTR[w * 256 + n * 16 + m] = acc_tr[r];
    }
    if ((m >> 2) == kg) redRR[w * 16 + m] = acc_rr[m & 3];
    __syncthreads();

    const int n  = t >> 4;
    const int mm = t & 15;
    const float tt = redTT[t] + redTT[256 + t] + redTT[512 + t] + redTT[768 + t];
    const float tr = redTR[t] + redTR[256 + t] + redTR[512 + t] + redTR[768 + t];

    if (slot != 6) {
        float* slotp = ws + (size_t)(b * 6 + slot) * 528;
        slotp[n * 32 + mm]      = tt;
        slotp[n * 32 + 16 + mm] = tr;
        if (t < 16)
            slotp[512 + t] = redRR[t] + redRR[16 + t] + redRR[32 + t] + redRR[48 + t];
        return;
    }

    // ---- slot 6 (level 2): finish the loss in-kernel ----
    Gs[n * 33 + mm]      = tt;
    Gs[n * 33 + 16 + mm] = tr;
    if (t < 16)
        rn2[t] = redRR[t] + redRR[16 + t] + redRR[32 + t] + redRR[48 + t];
    __syncthreads();

    if (t < 16) {
        tnS[t] = fmaxf(sqrtf(Gs[t * 33 + t]), NTX_EPS);
        rnS[t] = fmaxf(sqrtf(rn2[t]), NTX_EPS);
    }
    __syncthreads();

    float loss = 0.f;
    if (t < 16) {
        const int nn = t;
        const float itn = 2.0f / tnS[nn];        // includes 1/temperature
        float lg[32];
#pragma unroll
        for (int j = 0; j < 16; ++j)
            lg[j] = Gs[nn * 33 + 16 + j] * itn / rnS[j];   // s_tr row
#pragma unroll
        for (int k = 0; k < 16; ++k)
            lg[16 + k] = Gs[nn * 33 + k] * itn / tnS[k];   // s_tt row
        const float pos = lg[nn];
        float mx = -3.4e38f;
#pragma unroll
        for (int j = 0; j < 32; ++j)
            mx = (j == 16 + nn) ? mx : fmaxf(mx, lg[j]);   // exclude tt diag
        float sm = 0.f;
#pragma unroll
        for (int j = 0; j < 32; ++j)
            sm += (j == 16 + nn) ? 0.f : expf(lg[j] - mx);
        loss = logf(sm) + mx - pos;
    }
    loss += __shfl_xor(loss, 1, 64);
    loss += __shfl_xor(loss, 2, 64);
    loss += __shfl_xor(loss, 4, 64);
    loss += __shfl_xor(loss, 8, 64);
    if (t == 0) ws[LOSS_OFF + b * 3 + 2] = loss;    // no atomic
}

// Kernel 2: sum partial Grams for levels 0/1 and do the logsumexp.
__global__ __launch_bounds__(64)
void ntxent_finish(const float* __restrict__ ws_in, float* __restrict__ ws)
{
    __shared__ float G[16][33];
    __shared__ float rn2s[16];
    __shared__ float tn[16], rn[16];

    const int bid = blockIdx.x;
    const int b   = bid >> 1;
    const int lvl = bid & 1;
    const int base = b * 6 + (lvl ? 4 : 0);
    const int cnt  = lvl ? 2 : 4;
    const int l = threadIdx.x;

    for (int e = l; e < 512; e += 64) {
        float s = 0.f;
        for (int c = 0; c < cnt; ++c) s += ws_in[(size_t)(base + c) * 528 + e];
        G[e >> 5][e & 31] = s;
    }
    if (l < 16) {
        float s = 0.f;
        for (int c = 0; c < cnt; ++c) s += ws_in[(size_t)(base + c) * 528 + 512 + l];
        rn2s[l] = s;
    }
    __syncthreads();
    if (l < 16) {
        tn[l] = fmaxf(sqrtf(G[l][l]), NTX_EPS);
        rn[l] = fmaxf(sqrtf(rn2s[l]), NTX_EPS);
    }
    __syncthreads();

    float loss = 0.f;
    if (l < 16) {
        const int n = l;
        const float itn = 2.0f / tn[n];
        float lg[32];
#pragma unroll
        for (int j = 0; j < 16; ++j)
            lg[j] = G[n][16 + j] * itn / rn[j];
#pragma unroll
        for (int k = 0; k < 16; ++k)
            lg[16 + k] = G[n][k] * itn / tn[k];
        const float pos = lg[n];
        float mx = -3.4e38f;
#pragma unroll
        for (int j = 0; j < 32; ++j)
            mx = (j == 16 + n) ? mx : fmaxf(mx, lg[j]);
        float sm = 0.f;
#pragma unroll
        for (int j = 0; j < 32; ++j)
            sm += (j == 16 + n) ? 0.f : expf(lg[j] - mx);
        loss = logf(sm) + mx - pos;
    }
    loss += __shfl_xor(loss, 1, 64);
    loss += __shfl_xor(loss, 2, 64);
    loss += __shfl_xor(loss, 4, 64);
    loss += __shfl_xor(loss, 8, 64);
    if (l == 0) ws[LOSS_OFF + b * 3 + lvl] = loss;  // no atomic
}

// Kernel 3: single block sums the 768 per-(b,lvl) losses -> out[0].
__global__ __launch_bounds__(256)
void ntxent_sum(const float* __restrict__ ws, float* __restrict__ out)
{
    __shared__ float partial[4];
    const int t = threadIdx.x;
    float s = 0.f;
    for (int i = t; i < 768; i += 256) s += ws[LOSS_OFF + i];
    s += __shfl_xor(s, 1, 64);
    s += __shfl_xor(s, 2, 64);
    s += __shfl_xor(s, 4, 64);
    s += __shfl_xor(s, 8, 64);
    s += __shfl_xor(s, 16, 64);
    s += __shfl_xor(s, 32, 64);
    if ((t & 63) == 0) partial[t >> 6] = s;
    __syncthreads();
    if (t == 0)
        out[0] = (partial[0] + partial[1] + partial[2] + partial[3])
                 * (1.0f / 512.0f);
}

extern "C" void kernel_launch(void* const* d_in, const int* in_sizes, int n_in,
                              void* d_out, int out_size, void* d_ws, size_t ws_size,
                              hipStream_t stream) {
    const float* ts0 = (const float*)d_in[0];
    const float* rs0 = (const float*)d_in[1];
    const float* ts1 = (const float*)d_in[2];
    const float* rs1 = (const float*)d_in[3];
    const float* ts2 = (const float*)d_in[4];
    const float* rs2 = (const float*)d_in[5];
    float* out = (float*)d_out;
    float* ws  = (float*)d_ws;

    const int B = in_sizes[0] / (16 * 4096);   // 256
    hipLaunchKernelGGL(ntxent_partial, dim3(B * 7), dim3(256), 0, stream,
                       ts0, rs0, ts1, rs1, ts2, rs2, ws);
    hipLaunchKernelGGL(ntxent_finish, dim3(B * 2), dim3(64), 0, stream,
                       ws, ws);
    hipLaunchKernelGGL(ntxent_sum, dim3(1), dim3(256), 0, stream,
                       ws, out);
}